// Round 1
// 499.455 us; speedup vs baseline: 1.2339x; 1.2339x over previous
//
#include <hip/hip_runtime.h>

// Problem constants (match reference setup_inputs)
#define H_DIM   4096   // input features (K of the GEMM)
#define M_DIM   4096   // output features (W rows = C cols)
#define N_ROWS  8192   // B*S flattened x rows
#define NNZ_ROW 2048
#define NT      (H_DIM / 64)   // 64 K-tiles of BK=64

typedef __bf16 bf16x8 __attribute__((ext_vector_type(8)));
typedef float  f32x4  __attribute__((ext_vector_type(4)));

// fp32 -> bf16 round-to-nearest-even on raw bits
__device__ __forceinline__ unsigned short f2bf(float f) {
    unsigned int u = __float_as_uint(f);
    u += 0x7fffu + ((u >> 16) & 1u);
    return (unsigned short)(u >> 16);
}

// async global->LDS, 16B/lane; LDS dst = wave-uniform base + lane*16
__device__ __forceinline__ void gld_lds16(const void* g, void* l) {
    __builtin_amdgcn_global_load_lds(
        (__attribute__((address_space(1))) const void*)g,
        (__attribute__((address_space(3))) void*)l,
        16, 0, 0);
}

// raw workgroup barrier with compiler fences (no vmcnt drain!)
__device__ __forceinline__ void wg_barrier() {
    __builtin_amdgcn_sched_barrier(0);
    asm volatile("" ::: "memory");
    __builtin_amdgcn_s_barrier();
    asm volatile("" ::: "memory");
    __builtin_amdgcn_sched_barrier(0);
}

// rule #18: sched_barrier(0) right after an inline-asm lgkmcnt wait
#define LGKM0_FENCE() do { \
    asm volatile("s_waitcnt lgkmcnt(0)" ::: "memory"); \
    __builtin_amdgcn_sched_barrier(0); \
} while (0)

// ---------------------------------------------------------------------------
// Kernel 1: decode CSR into dense ROW-MAJOR bf16 W [M][H].
// Block handles 4 consecutive rows; scatter into LDS, linear write out
// (conflict-free LDS read, fully coalesced 16B global stores).
// ---------------------------------------------------------------------------
__global__ __launch_bounds__(256) void decode_w_kernel(
        const float* __restrict__ values,
        const int*   __restrict__ col_idx,
        unsigned short* __restrict__ W) {
    __shared__ unsigned short buf[4 * H_DIM];      // 32 KiB
    const int r4 = blockIdx.x;                     // rows 4*r4 .. 4*r4+3
    const int t  = threadIdx.x;

    uint4 z = make_uint4(0u, 0u, 0u, 0u);
    #pragma unroll
    for (int i = 0; i < 8; ++i) ((uint4*)buf)[i * 256 + t] = z;
    __syncthreads();

    #pragma unroll
    for (int rl = 0; rl < 4; ++rl) {
        const long base = ((long)(4 * r4 + rl)) * NNZ_ROW;
        #pragma unroll
        for (int j = 0; j < NNZ_ROW; j += 256) {
            float v = values[base + j + t];
            int   c = col_idx[base + j + t];
            buf[rl * H_DIM + c] = f2bf(v);
        }
    }
    __syncthreads();

    const long wbase = (long)(4 * r4) * H_DIM;
    #pragma unroll
    for (int it = 0; it < 8; ++it) {
        const int s = it * 256 + t;                // uint4 slot 0..2047
        *(uint4*)&W[wbase + (long)s * 8] = *(const uint4*)&buf[s * 8];
    }
}

// ---------------------------------------------------------------------------
// Kernel 2: x fp32 -> bf16 row-major. float4 load (16B), 8B store, grid-stride.
// ---------------------------------------------------------------------------
__global__ __launch_bounds__(256) void convert_x_kernel(
        const float4* __restrict__ x, unsigned long long* __restrict__ xb) {
    const long total = (long)N_ROWS * H_DIM / 4;
    for (long i = (long)blockIdx.x * 256 + threadIdx.x; i < total;
         i += (long)gridDim.x * 256) {
        float4 a = x[i];
        union { unsigned short s[4]; unsigned long long v; } r;
        r.s[0] = f2bf(a.x); r.s[1] = f2bf(a.y);
        r.s[2] = f2bf(a.z); r.s[3] = f2bf(a.w);
        xb[i] = r.v;
    }
}

// ---------------------------------------------------------------------------
// Kernel 3: C[8192,4096] = Xb @ W^T. 256x256 tile, BK=64, 8 waves (2Mx4N),
// 128 KiB LDS double-buffer, global_load_lds staging with pre-swizzled source
// (chunk ^= row&7), counted vmcnt(8) across raw barriers, 4 phases/K-tile,
// setprio around each 16-MFMA cluster. XCD-bijective grid swizzle.
// ---------------------------------------------------------------------------
__global__ __launch_bounds__(512, 2) void gemm256_kernel(
        const unsigned short* __restrict__ A,    // Xb row-major [8192][4096]
        const unsigned short* __restrict__ B,    // W  row-major [4096][4096]
        float* __restrict__ C) {
    // per 64KB buffer: A half0 | A half1 | B half0 | B half1, each [128][64] bf16
    __shared__ unsigned short lds[2 * 32768];    // 128 KiB

    const int t    = threadIdx.x;
    const int lane = t & 63;
    const int wid  = t >> 6;
    const int wm   = wid >> 2;        // 0..1 : 128-row slab
    const int wn   = wid & 3;         // 0..3 : 64-col slab

    // XCD swizzle: 512 blocks, 8 XCDs -> each XCD owns 2 ctiles (4MB B ~ L2)
    const int bid   = blockIdx.x;
    const int wg    = (bid & 7) * 64 + (bid >> 3);
    const int ctile = wg >> 5;        // 0..15
    const int rtile = wg & 31;        // 0..31
    const long row0 = (long)rtile * 256;
    const long col0 = (long)ctile * 256;

    // ---- staging: thread t owns 16B chunk (row rr, chunk (t&7)^(rr&7))
    // of each 128x64 half-tile; LDS dest is linear (slot t and 512+t).
    const int rr = t >> 3;                       // 0..63
    const int cc = ((t & 7) ^ (rr & 7)) * 8;     // pre-swizzled source chunk
    const unsigned short* pA = A + (row0 + rr) * H_DIM + cc;
    const unsigned short* pB = B + (col0 + rr) * H_DIM + cc;
    unsigned short* const Ld = &lds[t * 8];

#define STAGE(bufo) do { \
    gld_lds16(pA,               Ld + (bufo));         \
    gld_lds16(pA +  64 * H_DIM, Ld + (bufo) + 4096);  \
    gld_lds16(pA + 128 * H_DIM, Ld + (bufo) + 8192);  \
    gld_lds16(pA + 192 * H_DIM, Ld + (bufo) + 12288); \
    gld_lds16(pB,               Ld + (bufo) + 16384); \
    gld_lds16(pB +  64 * H_DIM, Ld + (bufo) + 20480); \
    gld_lds16(pB + 128 * H_DIM, Ld + (bufo) + 24576); \
    gld_lds16(pB + 192 * H_DIM, Ld + (bufo) + 28672); \
    pA += 64; pB += 64; \
} while (0)

    // ---- compute-side addressing. row&7 == fr&7 for every fragment row,
    // so the read-side xor is a lane constant: chunk = (kk*4+jq) ^ (fr&7).
    const int fr = lane & 15;
    const int jq = lane >> 4;
    const int cx = fr & 7;
    const int off0 = ((0 * 4 + jq) ^ cx) * 8;    // kk=0 chunk, elems
    const int off1 = ((1 * 4 + jq) ^ cx) * 8;    // kk=1 chunk, elems
    const int aoff = wm * 8192 + fr * 64;
    const int boff = 16384 + (wn >> 1) * 8192 + ((wn & 1) * 64 + fr) * 64;

    f32x4 acc[8][4];
    #pragma unroll
    for (int i = 0; i < 8; ++i)
        #pragma unroll
        for (int j = 0; j < 4; ++j) acc[i][j] = (f32x4)0.0f;

    auto TILE = [&](const int cb) {
        const unsigned short* Ab = &lds[cb + aoff];
        const unsigned short* Bb = &lds[cb + boff];
        bf16x8 a[4][2], b0[2][2], b1[2][2];
        // -------- phase 1: quadrant (i 0-3, j 0-1), 12 ds_read + 16 MFMA
        #pragma unroll
        for (int i = 0; i < 4; ++i) {
            a[i][0] = *(const bf16x8*)(Ab + i * 1024 + off0);
            a[i][1] = *(const bf16x8*)(Ab + i * 1024 + off1);
        }
        #pragma unroll
        for (int j = 0; j < 2; ++j) {
            b0[j][0] = *(const bf16x8*)(Bb + j * 1024 + off0);
            b0[j][1] = *(const bf16x8*)(Bb + j * 1024 + off1);
        }
        LGKM0_FENCE();
        __builtin_amdgcn_s_setprio(1);
        #pragma unroll
        for (int i = 0; i < 4; ++i)
            #pragma unroll
            for (int j = 0; j < 2; ++j) {
                acc[i][j] = __builtin_amdgcn_mfma_f32_16x16x32_bf16(
                                a[i][0], b0[j][0], acc[i][j], 0, 0, 0);
                acc[i][j] = __builtin_amdgcn_mfma_f32_16x16x32_bf16(
                                a[i][1], b0[j][1], acc[i][j], 0, 0, 0);
            }
        __builtin_amdgcn_s_setprio(0);
        // -------- phase 2: quadrant (i 0-3, j 2-3), 4 ds_read + 16 MFMA
        #pragma unroll
        for (int j = 0; j < 2; ++j) {
            b1[j][0] = *(const bf16x8*)(Bb + (2 + j) * 1024 + off0);
            b1[j][1] = *(const bf16x8*)(Bb + (2 + j) * 1024 + off1);
        }
        LGKM0_FENCE();
        __builtin_amdgcn_s_setprio(1);
        #pragma unroll
        for (int i = 0; i < 4; ++i)
            #pragma unroll
            for (int j = 0; j < 2; ++j) {
                acc[i][2 + j] = __builtin_amdgcn_mfma_f32_16x16x32_bf16(
                                    a[i][0], b1[j][0], acc[i][2 + j], 0, 0, 0);
                acc[i][2 + j] = __builtin_amdgcn_mfma_f32_16x16x32_bf16(
                                    a[i][1], b1[j][1], acc[i][2 + j], 0, 0, 0);
            }
        __builtin_amdgcn_s_setprio(0);
        // -------- phase 3: quadrant (i 4-7, j 2-3), 8 ds_read + 16 MFMA
        #pragma unroll
        for (int i = 0; i < 4; ++i) {
            a[i][0] = *(const bf16x8*)(Ab + (4 + i) * 1024 + off0);
            a[i][1] = *(const bf16x8*)(Ab + (4 + i) * 1024 + off1);
        }
        LGKM0_FENCE();
        __builtin_amdgcn_s_setprio(1);
        #pragma unroll
        for (int i = 0; i < 4; ++i)
            #pragma unroll
            for (int j = 0; j < 2; ++j) {
                acc[4 + i][2 + j] = __builtin_amdgcn_mfma_f32_16x16x32_bf16(
                                        a[i][0], b1[j][0], acc[4 + i][2 + j], 0, 0, 0);
                acc[4 + i][2 + j] = __builtin_amdgcn_mfma_f32_16x16x32_bf16(
                                        a[i][1], b1[j][1], acc[4 + i][2 + j], 0, 0, 0);
            }
        __builtin_amdgcn_s_setprio(0);
        // -------- phase 4: quadrant (i 4-7, j 0-1), 0 ds_read + 16 MFMA
        __builtin_amdgcn_s_setprio(1);
        #pragma unroll
        for (int i = 0; i < 4; ++i)
            #pragma unroll
            for (int j = 0; j < 2; ++j) {
                acc[4 + i][j] = __builtin_amdgcn_mfma_f32_16x16x32_bf16(
                                    a[i][0], b0[j][0], acc[4 + i][j], 0, 0, 0);
                acc[4 + i][j] = __builtin_amdgcn_mfma_f32_16x16x32_bf16(
                                    a[i][1], b0[j][1], acc[4 + i][j], 0, 0, 0);
            }
        __builtin_amdgcn_s_setprio(0);
    };

    // ---- main loop: stage tile T+1, vmcnt(8) keeps it in flight across both
    // barriers (T4: never drain to 0 in the loop).
    STAGE(0);                                    // tile 0 -> buf0
    #pragma unroll 1
    for (int kt = 0; kt < NT - 2; kt += 2) {
        STAGE(32768);                            // tile kt+1 -> buf1
        asm volatile("s_waitcnt vmcnt(8)" ::: "memory");
        wg_barrier();
        TILE(0);                                 // compute tile kt
        wg_barrier();
        STAGE(0);                                // tile kt+2 -> buf0
        asm volatile("s_waitcnt vmcnt(8)" ::: "memory");
        wg_barrier();
        TILE(32768);                             // compute tile kt+1
        wg_barrier();
    }
    STAGE(32768);                                // tile 63 -> buf1
    asm volatile("s_waitcnt vmcnt(8)" ::: "memory");
    wg_barrier();
    TILE(0);                                     // tile 62
    wg_barrier();
    asm volatile("s_waitcnt vmcnt(0)" ::: "memory");
    wg_barrier();
    TILE(32768);                                 // tile 63

#undef STAGE

    // ---- epilogue: D col = lane&15, row = (lane>>4)*4 + reg  [m89/m91]
    const int dcol = lane & 15;
    const int dr4  = (lane >> 4) * 4;
    const long crow = row0 + wm * 128;
    const int  ccol = (int)col0 + wn * 64 + dcol;
    #pragma unroll
    for (int i = 0; i < 8; ++i) {
        float* cp = C + (crow + i * 16 + dr4) * M_DIM + ccol;
        #pragma unroll
        for (int j = 0; j < 4; ++j)
            #pragma unroll
            for (int q = 0; q < 4; ++q)
                cp[(long)q * M_DIM + j * 16] = acc[i][j][q];
    }
}

// ---------------------------------------------------------------------------
// Fallback if ws too small: naive fp32 sparse dot (correct, slow).
// ---------------------------------------------------------------------------
__global__ __launch_bounds__(256) void naive_kernel(
        const float* __restrict__ x, const float* __restrict__ vals,
        const int* __restrict__ cols, float* __restrict__ out) {
    const long idx = blockIdx.x * 256L + threadIdx.x;
    const int  m   = (int)(idx & (M_DIM - 1));
    const long n   = idx >> 12;
    const float* xr = x + n * H_DIM;
    const float* v  = vals + (long)m * NNZ_ROW;
    const int*   c  = cols + (long)m * NNZ_ROW;
    float s = 0.f;
    for (int j = 0; j < NNZ_ROW; ++j) s += v[j] * xr[c[j]];
    out[idx] = s;
}

extern "C" void kernel_launch(void* const* d_in, const int* in_sizes, int n_in,
                              void* d_out, int out_size, void* d_ws, size_t ws_size,
                              hipStream_t stream) {
    const float* x       = (const float*)d_in[0];
    const float* values  = (const float*)d_in[1];
    const int*   col_idx = (const int*)d_in[2];
    float* out = (float*)d_out;

    const size_t wbytes = (size_t)M_DIM * H_DIM * sizeof(unsigned short);   // 33.5 MB
    const size_t xbytes = (size_t)N_ROWS * H_DIM * sizeof(unsigned short);  // 67 MB

    if (ws_size >= wbytes + xbytes) {
        unsigned short* Wd = (unsigned short*)d_ws;
        unsigned short* Xb = (unsigned short*)((char*)d_ws + wbytes);

        decode_w_kernel<<<M_DIM / 4, 256, 0, stream>>>(values, col_idx, Wd);
        convert_x_kernel<<<4096, 256, 0, stream>>>(
            (const float4*)x, (unsigned long long*)Xb);
        gemm256_kernel<<<512, 512, 0, stream>>>(Xb, Wd, out);
    } else {
        naive_kernel<<<(int)((long)N_ROWS * M_DIM / 256), 256, 0, stream>>>(
            x, values, col_idx, out);
    }
}

// Round 2
// 494.058 us; speedup vs baseline: 1.2474x; 1.0109x over previous
//
#include <hip/hip_runtime.h>

// Problem constants (match reference setup_inputs)
#define H_DIM   4096   // input features (K of the GEMM)
#define M_DIM   4096   // output features (W rows = C cols)
#define N_ROWS  8192   // B*S flattened x rows
#define NNZ_ROW 2048
#define NT      (H_DIM / 64)   // 64 K-tiles of BK=64

typedef __bf16 bf16x8 __attribute__((ext_vector_type(8)));
typedef float  f32x4  __attribute__((ext_vector_type(4)));

// fp32 -> bf16 round-to-nearest-even on raw bits
__device__ __forceinline__ unsigned short f2bf(float f) {
    unsigned int u = __float_as_uint(f);
    u += 0x7fffu + ((u >> 16) & 1u);
    return (unsigned short)(u >> 16);
}

// async global->LDS, 16B/lane; LDS dst = wave-uniform base + lane*16
__device__ __forceinline__ void gld_lds16(const void* g, void* l) {
    __builtin_amdgcn_global_load_lds(
        (__attribute__((address_space(1))) const void*)g,
        (__attribute__((address_space(3))) void*)l,
        16, 0, 0);
}

// raw workgroup barrier with compiler fences (no vmcnt drain!)
__device__ __forceinline__ void wg_barrier() {
    __builtin_amdgcn_sched_barrier(0);
    asm volatile("" ::: "memory");
    __builtin_amdgcn_s_barrier();
    asm volatile("" ::: "memory");
    __builtin_amdgcn_sched_barrier(0);
}

// rule #18: sched_barrier(0) right after an inline-asm waitcnt
#define LGKM0_FENCE() do { \
    asm volatile("s_waitcnt lgkmcnt(0)" ::: "memory"); \
    __builtin_amdgcn_sched_barrier(0); \
} while (0)

#define VMCNT(n) do { \
    asm volatile("s_waitcnt vmcnt(" #n ")" ::: "memory"); \
    __builtin_amdgcn_sched_barrier(0); \
} while (0)

// ---------------------------------------------------------------------------
// Kernel 1: decode CSR into dense ROW-MAJOR bf16 W [M][H].
// ---------------------------------------------------------------------------
__global__ __launch_bounds__(256) void decode_w_kernel(
        const float* __restrict__ values,
        const int*   __restrict__ col_idx,
        unsigned short* __restrict__ W) {
    __shared__ unsigned short buf[4 * H_DIM];      // 32 KiB
    const int r4 = blockIdx.x;                     // rows 4*r4 .. 4*r4+3
    const int t  = threadIdx.x;

    uint4 z = make_uint4(0u, 0u, 0u, 0u);
    #pragma unroll
    for (int i = 0; i < 8; ++i) ((uint4*)buf)[i * 256 + t] = z;
    __syncthreads();

    #pragma unroll
    for (int rl = 0; rl < 4; ++rl) {
        const long base = ((long)(4 * r4 + rl)) * NNZ_ROW;
        #pragma unroll
        for (int j = 0; j < NNZ_ROW; j += 256) {
            float v = values[base + j + t];
            int   c = col_idx[base + j + t];
            buf[rl * H_DIM + c] = f2bf(v);
        }
    }
    __syncthreads();

    const long wbase = (long)(4 * r4) * H_DIM;
    #pragma unroll
    for (int it = 0; it < 8; ++it) {
        const int s = it * 256 + t;                // uint4 slot 0..2047
        *(uint4*)&W[wbase + (long)s * 8] = *(const uint4*)&buf[s * 8];
    }
}

// ---------------------------------------------------------------------------
// Kernel 2: x fp32 -> bf16 row-major. float4 load (16B), 8B store, grid-stride.
// ---------------------------------------------------------------------------
__global__ __launch_bounds__(256) void convert_x_kernel(
        const float4* __restrict__ x, unsigned long long* __restrict__ xb) {
    const long total = (long)N_ROWS * H_DIM / 4;
    for (long i = (long)blockIdx.x * 256 + threadIdx.x; i < total;
         i += (long)gridDim.x * 256) {
        float4 a = x[i];
        union { unsigned short s[4]; unsigned long long v; } r;
        r.s[0] = f2bf(a.x); r.s[1] = f2bf(a.y);
        r.s[2] = f2bf(a.z); r.s[3] = f2bf(a.w);
        xb[i] = r.v;
    }
}

// ---------------------------------------------------------------------------
// Kernel 3: C[8192,4096] = Xb @ W^T. 256x256 tile, BK=64, 8 waves (2Mx4N),
// 128 KiB LDS double-buffer. TRUE 8-phase-per-pair schedule (m201 template):
// per phase {ds_read ∥ 2-4 gld_lds restage -> barrier -> lgkm0 -> setprio MFMA
// -> barrier}, counted vmcnt(8) once per K-tile, never drained in the loop.
// Stage slots chosen per chunk-level clobber analysis:
//   ph2: A chunks {0,2} (dead after ph1)   ph3: B chunks {0..3} (dead after ph2)
//   ph4: A chunks {1,3} (dead after ph3)
// XOR-swizzled source + matching read swizzle (rule #21). XCD-bijective grid.
// ---------------------------------------------------------------------------
__global__ __launch_bounds__(512, 2) void gemm256_kernel(
        const unsigned short* __restrict__ A,    // Xb row-major [8192][4096]
        const unsigned short* __restrict__ B,    // W  row-major [4096][4096]
        float* __restrict__ C) {
    // per 64KB buffer: A chunks 0-3 (64 rows each) | B chunks 0-3
    __shared__ unsigned short lds[2 * 32768];    // 128 KiB

    const int t    = threadIdx.x;
    const int lane = t & 63;
    const int wid  = t >> 6;
    const int wm   = wid >> 2;        // 0..1 : 128-row slab
    const int wn   = wid & 3;         // 0..3 : 64-col slab

    // XCD swizzle: 512 blocks, 8 XCDs -> each XCD owns 2 ctiles (4MB B ~ L2)
    const int bid   = blockIdx.x;
    const int wg    = (bid & 7) * 64 + (bid >> 3);
    const int ctile = wg >> 5;        // 0..15
    const int rtile = wg & 31;        // 0..31
    const long row0 = (long)rtile * 256;
    const long col0 = (long)ctile * 256;

    // ---- staging: thread t owns 16B chunk (row rr, chunk (t&7)^(rr&7))
    // of each 64x64 chunk; LDS dest is linear (slot t per chunk).
    const int rr = t >> 3;                       // 0..63
    const int cc = ((t & 7) ^ (rr & 7)) * 8;     // pre-swizzled source chunk
    const unsigned short* pA_ = A + (row0 + rr) * H_DIM + cc;
    const unsigned short* pB_ = B + (col0 + rr) * H_DIM + cc;
    unsigned short* const Ld = &lds[t * 8];

    // A chunks: c=rows 64c..64c+63 at LDS elem c*4096; B chunks at 16384+c*4096
#define SAE(kt, bo) do { /* A chunks 0,2 */ \
    gld_lds16(pA_ + (long)(kt) * 64,               Ld + (bo));        \
    gld_lds16(pA_ + (long)(kt) * 64 + 128 * H_DIM, Ld + (bo) + 8192); \
} while (0)
#define SAO(kt, bo) do { /* A chunks 1,3 */ \
    gld_lds16(pA_ + (long)(kt) * 64 +  64 * H_DIM, Ld + (bo) + 4096);  \
    gld_lds16(pA_ + (long)(kt) * 64 + 192 * H_DIM, Ld + (bo) + 12288); \
} while (0)
#define SBALL(kt, bo) do { /* B chunks 0-3 */ \
    gld_lds16(pB_ + (long)(kt) * 64,               Ld + (bo) + 16384); \
    gld_lds16(pB_ + (long)(kt) * 64 +  64 * H_DIM, Ld + (bo) + 20480); \
    gld_lds16(pB_ + (long)(kt) * 64 + 128 * H_DIM, Ld + (bo) + 24576); \
    gld_lds16(pB_ + (long)(kt) * 64 + 192 * H_DIM, Ld + (bo) + 28672); \
} while (0)

    // ---- compute-side addressing (identical to verified round-1 kernel)
    const int fr = lane & 15;
    const int jq = lane >> 4;
    const int cx = fr & 7;
    const int off0 = ((0 * 4 + jq) ^ cx) * 8;    // kk=0 chunk, elems
    const int off1 = ((1 * 4 + jq) ^ cx) * 8;    // kk=1 chunk, elems
    const int aoff = wm * 8192 + fr * 64;
    const int boff = 16384 + (wn >> 1) * 8192 + ((wn & 1) * 64 + fr) * 64;

    f32x4 acc[8][4];
    #pragma unroll
    for (int i = 0; i < 8; ++i)
        #pragma unroll
        for (int j = 0; j < 4; ++j) acc[i][j] = (f32x4)0.0f;

    bf16x8 a[4][2], b0[2][2], b1[2][2];

    auto rdA = [&](int cb, int base4) {
        #pragma unroll
        for (int i = 0; i < 4; ++i) {
            a[i][0] = *(const bf16x8*)&lds[cb + aoff + (base4 + i) * 1024 + off0];
            a[i][1] = *(const bf16x8*)&lds[cb + aoff + (base4 + i) * 1024 + off1];
        }
    };
    auto rdB = [&](int cb, int base2, bf16x8 (&b)[2][2]) {
        #pragma unroll
        for (int j = 0; j < 2; ++j) {
            b[j][0] = *(const bf16x8*)&lds[cb + boff + (base2 + j) * 1024 + off0];
            b[j][1] = *(const bf16x8*)&lds[cb + boff + (base2 + j) * 1024 + off1];
        }
    };
    auto mm = [&](bf16x8 (&b)[2][2], int ib, int jb) {
        __builtin_amdgcn_s_setprio(1);
        #pragma unroll
        for (int i = 0; i < 4; ++i)
            #pragma unroll
            for (int j = 0; j < 2; ++j) {
                acc[ib + i][jb + j] = __builtin_amdgcn_mfma_f32_16x16x32_bf16(
                    a[i][0], b[j][0], acc[ib + i][jb + j], 0, 0, 0);
                acc[ib + i][jb + j] = __builtin_amdgcn_mfma_f32_16x16x32_bf16(
                    a[i][1], b[j][1], acc[ib + i][jb + j], 0, 0, 0);
            }
        __builtin_amdgcn_s_setprio(0);
    };

    // one K-tile in buffer cb, restaging tile st into the same buffer
    auto tileMain = [&](int cb, int st) {
        // ph1: reads A chunks {2wm}, B chunks (b0)
        rdA(cb, 0); rdB(cb, 0, b0);
        wg_barrier(); LGKM0_FENCE();
        mm(b0, 0, 0);
        wg_barrier();
        // ph2: reads B (b1); restage A chunks {0,2}
        rdB(cb, 2, b1);
        SAE(st, cb);
        wg_barrier(); LGKM0_FENCE();
        mm(b1, 0, 2);
        wg_barrier();
        // ph3: reads A chunks {2wm+1}; restage B chunks {0..3}
        rdA(cb, 4);
        SBALL(st, cb);
        wg_barrier(); LGKM0_FENCE();
        mm(b1, 4, 2);
        wg_barrier();
        // ph4: restage A chunks {1,3}; counted vmcnt -> other buffer ready
        SAO(st, cb);
        VMCNT(8);
        wg_barrier();
        mm(b0, 4, 0);
        wg_barrier();
    };
    auto tileLast = [&](int cb, bool drain) {
        rdA(cb, 0); rdB(cb, 0, b0);
        wg_barrier(); LGKM0_FENCE();
        mm(b0, 0, 0);
        wg_barrier();
        rdB(cb, 2, b1);
        wg_barrier(); LGKM0_FENCE();
        mm(b1, 0, 2);
        wg_barrier();
        rdA(cb, 4);
        wg_barrier(); LGKM0_FENCE();
        mm(b1, 4, 2);
        wg_barrier();
        if (drain) VMCNT(0);
        wg_barrier();
        mm(b0, 4, 0);
        wg_barrier();
    };

    // ---- prologue: stage tiles 0 (buf0) and 1 (buf1); wait tile 0 only
    SAE(0, 0); SAO(0, 0); SBALL(0, 0);
    SAE(1, 32768); SAO(1, 32768); SBALL(1, 32768);
    VMCNT(8);
    wg_barrier();

    #pragma unroll 1
    for (int kt = 0; kt < NT - 2; kt += 2) {
        tileMain(0,     kt + 2);      // compute kt,   restage kt+2 -> buf0
        tileMain(32768, kt + 3);      // compute kt+1, restage kt+3 -> buf1
    }
    tileLast(0, true);                // tile 62 (drain tile-63 loads at ph4)
    tileLast(32768, false);           // tile 63

#undef SAE
#undef SAO
#undef SBALL

    // ---- epilogue: D col = lane&15, row = (lane>>4)*4 + reg  [m89/m91]
    const int dcol = lane & 15;
    const int dr4  = (lane >> 4) * 4;
    const long crow = row0 + wm * 128;
    const int  ccol = (int)col0 + wn * 64 + dcol;
    #pragma unroll
    for (int i = 0; i < 8; ++i) {
        float* cp = C + (crow + i * 16 + dr4) * M_DIM + ccol;
        #pragma unroll
        for (int j = 0; j < 4; ++j)
            #pragma unroll
            for (int q = 0; q < 4; ++q)
                cp[(long)q * M_DIM + j * 16] = acc[i][j][q];
    }
}

// ---------------------------------------------------------------------------
// Fallback if ws too small: naive fp32 sparse dot (correct, slow).
// ---------------------------------------------------------------------------
__global__ __launch_bounds__(256) void naive_kernel(
        const float* __restrict__ x, const float* __restrict__ vals,
        const int* __restrict__ cols, float* __restrict__ out) {
    const long idx = blockIdx.x * 256L + threadIdx.x;
    const int  m   = (int)(idx & (M_DIM - 1));
    const long n   = idx >> 12;
    const float* xr = x + n * H_DIM;
    const float* v  = vals + (long)m * NNZ_ROW;
    const int*   c  = cols + (long)m * NNZ_ROW;
    float s = 0.f;
    for (int j = 0; j < NNZ_ROW; ++j) s += v[j] * xr[c[j]];
    out[idx] = s;
}

extern "C" void kernel_launch(void* const* d_in, const int* in_sizes, int n_in,
                              void* d_out, int out_size, void* d_ws, size_t ws_size,
                              hipStream_t stream) {
    const float* x       = (const float*)d_in[0];
    const float* values  = (const float*)d_in[1];
    const int*   col_idx = (const int*)d_in[2];
    float* out = (float*)d_out;

    const size_t wbytes = (size_t)M_DIM * H_DIM * sizeof(unsigned short);   // 33.5 MB
    const size_t xbytes = (size_t)N_ROWS * H_DIM * sizeof(unsigned short);  // 67 MB

    if (ws_size >= wbytes + xbytes) {
        unsigned short* Wd = (unsigned short*)d_ws;
        unsigned short* Xb = (unsigned short*)((char*)d_ws + wbytes);

        decode_w_kernel<<<M_DIM / 4, 256, 0, stream>>>(values, col_idx, Wd);
        convert_x_kernel<<<4096, 256, 0, stream>>>(
            (const float4*)x, (unsigned long long*)Xb);
        gemm256_kernel<<<512, 512, 0, stream>>>(Xb, Wd, out);
    } else {
        naive_kernel<<<(int)((long)N_ROWS * M_DIM / 256), 256, 0, stream>>>(
            x, values, col_idx, out);
    }
}